// Round 1
// baseline (1696.756 us; speedup 1.0000x reference)
//
#include <hip/hip_runtime.h>
#include <math.h>

#define DIM 768
#define SEQ 4096
#define BATCH 4
#define TOK (BATCH*SEQ)

typedef _Float16 f16;
typedef _Float16 f16x8 __attribute__((ext_vector_type(8)));
typedef _Float16 f16x4 __attribute__((ext_vector_type(4)));
typedef float f32x4 __attribute__((ext_vector_type(4)));

// ---------------- fp32 -> fp16 convert (vectorized) ----------------
__global__ void cvt_kernel(const float* __restrict__ src, f16* __restrict__ dst, int n4) {
    int i = blockIdx.x * blockDim.x + threadIdx.x;
    int stride = gridDim.x * blockDim.x;
    for (; i < n4; i += stride) {
        float4 v = ((const float4*)src)[i];
        f16x4 h = { (f16)v.x, (f16)v.y, (f16)v.z, (f16)v.w };
        ((f16x4*)dst)[i] = h;
    }
}

// ---------------- QKV projection GEMM ----------------
// Y[t][e] = sum_d xh[t][d] * Wh[e][d] + bias[e];  M=16384, N=2304 (Q|K|V), K=768
// 128x128 tile, 4 waves (2x2), each wave 64x64 = 4x4 MFMA tiles, frags direct from global.
__launch_bounds__(256, 2)
__global__ void proj_kernel(const f16* __restrict__ xh, const f16* __restrict__ Wh,
                            const float* __restrict__ bq, const float* __restrict__ bk,
                            const float* __restrict__ bv,
                            f16* __restrict__ Qh, f16* __restrict__ Kh, f16* __restrict__ VT) {
    int tid = threadIdx.x;
    int w = tid >> 6, l = tid & 63;
    int wr = w >> 1, wc = w & 1;
    int lr = l & 15, lq = l >> 4;
    int m0 = blockIdx.x * 128 + wr * 64;
    int n0 = blockIdx.y * 128 + wc * 64;

    f32x4 acc[4][4] = {};
    for (int k0 = 0; k0 < DIM; k0 += 32) {
        f16x8 af[4], bf[4];
#pragma unroll
        for (int mt = 0; mt < 4; ++mt)
            af[mt] = *(const f16x8*)&xh[(size_t)(m0 + mt*16 + lr) * DIM + k0 + lq*8];
#pragma unroll
        for (int nt = 0; nt < 4; ++nt)
            bf[nt] = *(const f16x8*)&Wh[(size_t)(n0 + nt*16 + lr) * DIM + k0 + lq*8];
#pragma unroll
        for (int mt = 0; mt < 4; ++mt)
#pragma unroll
            for (int nt = 0; nt < 4; ++nt)
                acc[mt][nt] = __builtin_amdgcn_mfma_f32_16x16x32_f16(af[mt], bf[nt], acc[mt][nt], 0, 0, 0);
    }

    int mat = (blockIdx.y * 128) / DIM;          // 0=Q, 1=K, 2=V (768 % 128 == 0, uniform per block)
    const float* bias = (mat == 0) ? bq : ((mat == 1) ? bk : bv);
#pragma unroll
    for (int nt = 0; nt < 4; ++nt) {
        int n = n0 + nt*16 + lr;
        int e = n - mat * DIM;
        float be = bias[e];
#pragma unroll
        for (int mt = 0; mt < 4; ++mt) {
            int tbase = m0 + mt*16 + lq*4;
            f32x4 a = acc[mt][nt];
#pragma unroll
            for (int q = 0; q < 4; ++q) {
                int t = tbase + q;
                f16 h = (f16)(a[q] + be);
                if (mat == 0)      Qh[(size_t)t * DIM + e] = h;
                else if (mat == 1) Kh[(size_t)t * DIM + e] = h;
                else               VT[((size_t)(t >> 12) * DIM + e) * SEQ + (t & (SEQ - 1))] = h;
            }
        }
    }
}

// ---------------- flash attention + LN + w_out dot ----------------
// 1 WG = 64 q-rows of one batch. 8 waves: wave (r in 0..3, c in 0..1) owns
// 16 q-rows (r) x 384 output-dims (c). Q frags in regs; K/V frags from global;
// softmax coordination via LDS. KV step = 32.
__launch_bounds__(512, 2)
__global__ void flash_kernel(const f16* __restrict__ Qh, const f16* __restrict__ Kh,
                             const f16* __restrict__ VT,
                             const float* __restrict__ gamma, const float* __restrict__ beta,
                             const float* __restrict__ w_out, const float* __restrict__ b_out,
                             float* __restrict__ out) {
    int tid = threadIdx.x;
    int w = tid >> 6, l = tid & 63;
    int r = w >> 1, c = w & 1;
    int lr = l & 15, lq = l >> 4;
    int b = blockIdx.y;
    int s0 = blockIdx.x * 64;

    __shared__ __attribute__((aligned(16))) float S_lds[64][40];
    __shared__ __attribute__((aligned(16))) f16  P_lds[64][40];
    __shared__ float row_m[64], row_l[64], row_scale[64];
    __shared__ float part[64][2][3];
    __shared__ float sgwred[2], sbwred[2];

    const f16* Qb = Qh + (size_t)(b * SEQ + s0) * DIM;
    const f16* Kb = Kh + (size_t)b * SEQ * DIM;
    const f16* Vb = VT + (size_t)b * DIM * SEQ;

    f16x8 qf[24];
    {
        const f16* qrow = Qb + (size_t)(r*16 + lr) * DIM + lq*8;
#pragma unroll
        for (int kc = 0; kc < 24; ++kc) qf[kc] = *(const f16x8*)(qrow + kc*32);
    }
    f32x4 acc[24] = {};
    if (tid < 64) { row_m[tid] = -INFINITY; row_l[tid] = 0.f; }
    __syncthreads();

    for (int kv0 = 0; kv0 < SEQ; kv0 += 32) {
        // ---- QK^T: this wave computes S[16 rows (r)][16 cols (c-half)]
        f32x4 s = {};
        const f16* krow = Kb + (size_t)(kv0 + c*16 + lr) * DIM + lq*8;
#pragma unroll
        for (int kc = 0; kc < 24; ++kc) {
            f16x8 kf = *(const f16x8*)(krow + kc*32);
            s = __builtin_amdgcn_mfma_f32_16x16x32_f16(qf[kc], kf, s, 0, 0, 0);
        }
        {
            int col = c*16 + lr;
            int rb = r*16 + lq*4;
#pragma unroll
            for (int q = 0; q < 4; ++q) S_lds[rb + q][col] = s[q];
        }
        __syncthreads();

        // ---- online-softmax stats (c==0 waves own their 16 rows)
        if (c == 0) {
            int row = r*16 + lr;
            const float4* p4 = (const float4*)&S_lds[row][lq*8];
            float4 v0 = p4[0], v1 = p4[1];
            float mx = fmaxf(fmaxf(fmaxf(v0.x, v0.y), fmaxf(v0.z, v0.w)),
                             fmaxf(fmaxf(v1.x, v1.y), fmaxf(v1.z, v1.w)));
            mx = fmaxf(mx, __shfl_xor(mx, 16));
            mx = fmaxf(mx, __shfl_xor(mx, 32));
            float m_old = row_m[row];
            float m_new = fmaxf(m_old, mx);
            float se = __expf(v0.x - m_new) + __expf(v0.y - m_new)
                     + __expf(v0.z - m_new) + __expf(v0.w - m_new)
                     + __expf(v1.x - m_new) + __expf(v1.y - m_new)
                     + __expf(v1.z - m_new) + __expf(v1.w - m_new);
            se += __shfl_xor(se, 16);
            se += __shfl_xor(se, 32);
            float scale = __expf(m_old - m_new);
            float l_new = row_l[row] * scale + se;
            if (lq == 0) { row_m[row] = m_new; row_l[row] = l_new; row_scale[row] = scale; }
        }
        __syncthreads();

        // ---- rescale acc, write P tile (fp16)
        {
            int rb = r*16 + lq*4;
            float sc[4], mn[4];
#pragma unroll
            for (int q = 0; q < 4; ++q) { sc[q] = row_scale[rb+q]; mn[q] = row_m[rb+q]; }
#pragma unroll
            for (int q = 0; q < 4; ++q) {
                float p = __expf(s[q] - mn[q]);
                P_lds[rb+q][c*16 + lr] = (f16)p;
            }
#pragma unroll
            for (int nt = 0; nt < 24; ++nt)
#pragma unroll
                for (int q = 0; q < 4; ++q) acc[nt][q] *= sc[q];
        }
        __syncthreads();

        // ---- PV: acc[16 rows][384 cols (c-slice)] += P[16x32] * V[32 x 384]
        {
            f16x8 pa = *(const f16x8*)&P_lds[r*16 + lr][lq*8];
            const f16* vcol = Vb + (size_t)(c*384 + lr) * SEQ + kv0 + lq*8;
#pragma unroll
            for (int nt = 0; nt < 24; ++nt) {
                f16x8 vf = *(const f16x8*)(vcol + (size_t)nt * 16 * SEQ);
                acc[nt] = __builtin_amdgcn_mfma_f32_16x16x32_f16(pa, vf, acc[nt], 0, 0, 0);
            }
        }
    }

    // ---- epilogue: y = acc / l; LayerNorm; dot with w_out
    int rb = r*16 + lq*4;
    float invl[4];
#pragma unroll
    for (int q = 0; q < 4; ++q) invl[q] = 1.0f / row_l[rb+q];
    float s1[4] = {0,0,0,0}, s2[4] = {0,0,0,0}, s3[4] = {0,0,0,0};
    float sgw = 0.f, sbw = 0.f;
#pragma unroll
    for (int nt = 0; nt < 24; ++nt) {
        int d = c*384 + nt*16 + lr;
        float g = gamma[d], wo = w_out[d], be = beta[d];
        float gw = g * wo;
        sgw += gw; sbw += be * wo;
#pragma unroll
        for (int q = 0; q < 4; ++q) {
            float y = acc[nt][q] * invl[q];
            s1[q] += y; s2[q] += y * y; s3[q] += y * gw;
        }
    }
#pragma unroll
    for (int mask = 1; mask <= 8; mask <<= 1) {
#pragma unroll
        for (int q = 0; q < 4; ++q) {
            s1[q] += __shfl_xor(s1[q], mask);
            s2[q] += __shfl_xor(s2[q], mask);
            s3[q] += __shfl_xor(s3[q], mask);
        }
        sgw += __shfl_xor(sgw, mask);
        sbw += __shfl_xor(sbw, mask);
    }
    if (lr == 0) {
#pragma unroll
        for (int q = 0; q < 4; ++q) {
            part[rb+q][c][0] = s1[q];
            part[rb+q][c][1] = s2[q];
            part[rb+q][c][2] = s3[q];
        }
        if (r == 0 && lq == 0) { sgwred[c] = sgw; sbwred[c] = sbw; }
    }
    __syncthreads();
    if (tid < 64) {
        int row = tid;
        float S1 = part[row][0][0] + part[row][1][0];
        float S2 = part[row][0][1] + part[row][1][1];
        float S3 = part[row][0][2] + part[row][1][2];
        float SGW = sgwred[0] + sgwred[1];
        float SBW = sbwred[0] + sbwred[1];
        const float inv_d = 1.0f / 768.0f;
        float mu = S1 * inv_d;
        float var = S2 * inv_d - mu * mu;
        float rstd = rsqrtf(var + 1e-5f);
        float o = rstd * (S3 - mu * SGW) + SBW + b_out[0];
        out[(size_t)b * SEQ + s0 + row] = o;
    }
}

// ---------------- launch ----------------
extern "C" void kernel_launch(void* const* d_in, const int* in_sizes, int n_in,
                              void* d_out, int out_size, void* d_ws, size_t ws_size,
                              hipStream_t stream) {
    const float* x     = (const float*)d_in[0];
    const float* Wq    = (const float*)d_in[1];
    const float* bq    = (const float*)d_in[2];
    const float* Wk    = (const float*)d_in[3];
    const float* bk    = (const float*)d_in[4];
    const float* Wv    = (const float*)d_in[5];
    const float* bv    = (const float*)d_in[6];
    const float* gamma = (const float*)d_in[7];
    const float* beta  = (const float*)d_in[8];
    const float* w_out = (const float*)d_in[9];
    const float* b_out = (const float*)d_in[10];
    float* out = (float*)d_out;

    // workspace layout (fp16): xh 25165824B | Wh 3538944B | Qh 25165824B | Kh 25165824B | VT 25165824B
    const size_t NEEDED = 104202240;
    if (ws_size < NEEDED) return;  // fail visibly (output stays poisoned) rather than corrupt

    char* ws = (char*)d_ws;
    f16* xh = (f16*)(ws);
    f16* Wh = (f16*)(ws + 25165824);
    f16* Qh = (f16*)(ws + 28704768);
    f16* Kh = (f16*)(ws + 53870592);
    f16* VT = (f16*)(ws + 79036416);

    cvt_kernel<<<2048, 256, 0, stream>>>(x, xh, TOK * DIM / 4);
    cvt_kernel<<<512, 256, 0, stream>>>(Wq, Wh,             DIM * DIM / 4);
    cvt_kernel<<<512, 256, 0, stream>>>(Wk, Wh + DIM * DIM, DIM * DIM / 4);
    cvt_kernel<<<512, 256, 0, stream>>>(Wv, Wh + 2 * DIM * DIM, DIM * DIM / 4);

    proj_kernel<<<dim3(128, 18), 256, 0, stream>>>(xh, Wh, bq, bk, bv, Qh, Kh, VT);
    flash_kernel<<<dim3(64, 4), 512, 0, stream>>>(Qh, Kh, VT, gamma, beta, w_out, b_out, out);
}

// Round 2
// 671.998 us; speedup vs baseline: 2.5249x; 2.5249x over previous
//
#include <hip/hip_runtime.h>
#include <math.h>
#include <stdint.h>

#define DIM 768
#define SEQ 4096
#define BATCH 4
#define TOK (BATCH*SEQ)
#define CH 1024                 // q-rows per batch per S-chunk
#define NCHUNK (SEQ/CH)

typedef _Float16 f16;
typedef _Float16 f16x8 __attribute__((ext_vector_type(8)));
typedef _Float16 f16x4 __attribute__((ext_vector_type(4)));
typedef float f32x4 __attribute__((ext_vector_type(4)));

// async global->LDS, 16B per lane; LDS dest must be wave-uniform base (lane*16 implicit)
#define GLOAD16(gp, lp) __builtin_amdgcn_global_load_lds( \
    (const __attribute__((address_space(1))) unsigned int*)(gp), \
    (__attribute__((address_space(3))) unsigned int*)(lp), 16, 0, 0)

// stage a 128x32 f16 A-tile and B-tile (8KB each) with 4 gload16 per thread
// seg = j*4 + w (8 segs of 1KB per tile); lane l covers row seg*16 + l/4, k-group (l&3)*8
#define STAGE2(As_, Ab_, lda_, Bs_, Bb_, ldb_, k0_) do {                              \
    GLOAD16((Ab_) + (size_t)(w*16 + srow)*(lda_) + (k0_) + skg,     &(As_)[w*512]);   \
    GLOAD16((Ab_) + (size_t)((4+w)*16 + srow)*(lda_) + (k0_) + skg, &(As_)[(4+w)*512]);\
    GLOAD16((Bb_) + (size_t)(w*16 + srow)*(ldb_) + (k0_) + skg,     &(Bs_)[w*512]);   \
    GLOAD16((Bb_) + (size_t)((4+w)*16 + srow)*(ldb_) + (k0_) + skg, &(Bs_)[(4+w)*512]);\
} while (0)

// ---------------- fp32 -> fp16 convert ----------------
__global__ void cvt_kernel(const float* __restrict__ src, f16* __restrict__ dst, int n4) {
    int i = blockIdx.x * blockDim.x + threadIdx.x;
    int stride = gridDim.x * blockDim.x;
    for (; i < n4; i += stride) {
        float4 v = ((const float4*)src)[i];
        f16x4 h = { (f16)v.x, (f16)v.y, (f16)v.z, (f16)v.w };
        ((f16x4*)dst)[i] = h;
    }
}

__global__ void zero_kernel(float* __restrict__ p, int n) {
    int i = blockIdx.x * blockDim.x + threadIdx.x;
    if (i < n) p[i] = 0.f;
}

// ---------------- QKV projection GEMM (LDS-staged m97 style) ----------------
__launch_bounds__(256, 2)
__global__ void proj_fast(const f16* __restrict__ xh, const f16* __restrict__ Wh,
                          const float* __restrict__ bq, const float* __restrict__ bk,
                          const float* __restrict__ bv,
                          f16* __restrict__ Qh, f16* __restrict__ Kh, f16* __restrict__ VT) {
    __shared__ f16 As[128*32];
    __shared__ f16 Bs[128*32];
    int tid = threadIdx.x;
    int w = tid >> 6, l = tid & 63;
    int wr = w >> 1, wc = w & 1;
    int lr = l & 15, lq = l >> 4;
    int srow = l >> 2, skg = (l & 3) * 8;

    const f16* Abase = xh + (size_t)blockIdx.x * 128 * DIM;
    const f16* Bbase = Wh + (size_t)blockIdx.y * 128 * DIM;

    f32x4 acc[4][4] = {};
    for (int k0 = 0; k0 < DIM; k0 += 32) {
        __syncthreads();
        STAGE2(As, Abase, DIM, Bs, Bbase, DIM, k0);
        __syncthreads();
        f16x8 af[4], bf[4];
#pragma unroll
        for (int mt = 0; mt < 4; ++mt) af[mt] = *(const f16x8*)&As[(wr*64 + mt*16 + lr)*32 + lq*8];
#pragma unroll
        for (int nt = 0; nt < 4; ++nt) bf[nt] = *(const f16x8*)&Bs[(wc*64 + nt*16 + lr)*32 + lq*8];
#pragma unroll
        for (int mt = 0; mt < 4; ++mt)
#pragma unroll
            for (int nt = 0; nt < 4; ++nt)
                acc[mt][nt] = __builtin_amdgcn_mfma_f32_16x16x32_f16(af[mt], bf[nt], acc[mt][nt], 0, 0, 0);
    }

    int m0 = blockIdx.x * 128 + wr * 64;
    int n0 = blockIdx.y * 128 + wc * 64;
    int mat = (blockIdx.y * 128) / DIM;          // 0=Q, 1=K, 2=V
    const float* bias = (mat == 0) ? bq : ((mat == 1) ? bk : bv);
#pragma unroll
    for (int nt = 0; nt < 4; ++nt) {
        int n = n0 + nt*16 + lr;
        int e = n - mat * DIM;
        float be = bias[e];
#pragma unroll
        for (int mt = 0; mt < 4; ++mt) {
            int tbase = m0 + mt*16 + lq*4;
            f32x4 a = acc[mt][nt];
#pragma unroll
            for (int q = 0; q < 4; ++q) {
                int t = tbase + q;
                f16 h = (f16)(a[q] + be);
                if (mat == 0)      Qh[(size_t)t * DIM + e] = h;
                else if (mat == 1) Kh[(size_t)t * DIM + e] = h;
                else               VT[((size_t)(t >> 12) * DIM + e) * SEQ + (t & (SEQ - 1))] = h;
            }
        }
    }
}

// ---------------- S = Q K^T for one chunk (fp16 out) ----------------
__launch_bounds__(256, 2)
__global__ void qkt_kernel(const f16* __restrict__ Qh, const f16* __restrict__ Kh,
                           f16* __restrict__ Sc, int c0) {
    __shared__ f16 As[128*32];
    __shared__ f16 Bs[128*32];
    int tid = threadIdx.x;
    int w = tid >> 6, l = tid & 63;
    int wr = w >> 1, wc = w & 1;
    int lr = l & 15, lq = l >> 4;
    int srow = l >> 2, skg = (l & 3) * 8;
    int b = blockIdx.z;

    const f16* Abase = Qh + ((size_t)b * SEQ + c0 + blockIdx.x * 128) * DIM;
    const f16* Bbase = Kh + (size_t)b * SEQ * DIM + (size_t)blockIdx.y * 128 * DIM;

    f32x4 acc[4][4] = {};
    for (int k0 = 0; k0 < DIM; k0 += 32) {
        __syncthreads();
        STAGE2(As, Abase, DIM, Bs, Bbase, DIM, k0);
        __syncthreads();
        f16x8 af[4], bf[4];
#pragma unroll
        for (int mt = 0; mt < 4; ++mt) af[mt] = *(const f16x8*)&As[(wr*64 + mt*16 + lr)*32 + lq*8];
#pragma unroll
        for (int nt = 0; nt < 4; ++nt) bf[nt] = *(const f16x8*)&Bs[(wc*64 + nt*16 + lr)*32 + lq*8];
#pragma unroll
        for (int mt = 0; mt < 4; ++mt)
#pragma unroll
            for (int nt = 0; nt < 4; ++nt)
                acc[mt][nt] = __builtin_amdgcn_mfma_f32_16x16x32_f16(af[mt], bf[nt], acc[mt][nt], 0, 0, 0);
    }

    size_t rowbase = (size_t)b * CH + blockIdx.x * 128 + wr * 64;
    int colbase = blockIdx.y * 128 + wc * 64;
#pragma unroll
    for (int mt = 0; mt < 4; ++mt)
#pragma unroll
        for (int q = 0; q < 4; ++q) {
            size_t row = rowbase + mt*16 + lq*4 + q;
#pragma unroll
            for (int nt = 0; nt < 4; ++nt)
                Sc[row * SEQ + colbase + nt*16 + lr] = (f16)acc[mt][nt][q];
        }
}

// ---------------- in-place row softmax (writes normalized P) ----------------
__launch_bounds__(256, 4)
__global__ void softmax_kernel(f16* __restrict__ S) {
    int tid = threadIdx.x;
    size_t row = blockIdx.x;
    f16* p = S + row * SEQ + tid * 16;
    f16x8 v0 = ((const f16x8*)p)[0];
    f16x8 v1 = ((const f16x8*)p)[1];
    float x[16];
#pragma unroll
    for (int i = 0; i < 8; ++i) { x[i] = (float)v0[i]; x[8+i] = (float)v1[i]; }
    float mx = x[0];
#pragma unroll
    for (int i = 1; i < 16; ++i) mx = fmaxf(mx, x[i]);
#pragma unroll
    for (int m = 1; m <= 32; m <<= 1) mx = fmaxf(mx, __shfl_xor(mx, m));
    __shared__ float redm[4], redl[4];
    int w = tid >> 6;
    if ((tid & 63) == 0) redm[w] = mx;
    __syncthreads();
    mx = fmaxf(fmaxf(redm[0], redm[1]), fmaxf(redm[2], redm[3]));
    float e[16]; float se = 0.f;
#pragma unroll
    for (int i = 0; i < 16; ++i) { e[i] = __expf(x[i] - mx); se += e[i]; }
#pragma unroll
    for (int m = 1; m <= 32; m <<= 1) se += __shfl_xor(se, m);
    if ((tid & 63) == 0) redl[w] = se;
    __syncthreads();
    float inv = 1.0f / (redl[0] + redl[1] + redl[2] + redl[3]);
    f16x8 o0, o1;
#pragma unroll
    for (int i = 0; i < 8; ++i) { o0[i] = (f16)(e[i] * inv); o1[i] = (f16)(e[8+i] * inv); }
    ((f16x8*)p)[0] = o0;
    ((f16x8*)p)[1] = o1;
}

// ---------------- O-tile = P * V^T with fused LN-partial epilogue ----------------
__launch_bounds__(256, 2)
__global__ void pv_kernel(const f16* __restrict__ P, const f16* __restrict__ VT,
                          const float* __restrict__ gamma, const float* __restrict__ w_out,
                          float* __restrict__ part, int c0) {
    __shared__ f16 As[128*32];
    __shared__ f16 Bs[128*32];
    int tid = threadIdx.x;
    int w = tid >> 6, l = tid & 63;
    int wr = w >> 1, wc = w & 1;
    int lr = l & 15, lq = l >> 4;
    int srow = l >> 2, skg = (l & 3) * 8;
    int b = blockIdx.z;

    const f16* Abase = P  + ((size_t)b * CH + blockIdx.x * 128) * SEQ;
    const f16* Bbase = VT + (size_t)b * DIM * SEQ + (size_t)blockIdx.y * 128 * SEQ;

    f32x4 acc[4][4] = {};
    for (int k0 = 0; k0 < SEQ; k0 += 32) {
        __syncthreads();
        STAGE2(As, Abase, SEQ, Bs, Bbase, SEQ, k0);
        __syncthreads();
        f16x8 af[4], bf[4];
#pragma unroll
        for (int mt = 0; mt < 4; ++mt) af[mt] = *(const f16x8*)&As[(wr*64 + mt*16 + lr)*32 + lq*8];
#pragma unroll
        for (int nt = 0; nt < 4; ++nt) bf[nt] = *(const f16x8*)&Bs[(wc*64 + nt*16 + lr)*32 + lq*8];
#pragma unroll
        for (int mt = 0; mt < 4; ++mt)
#pragma unroll
            for (int nt = 0; nt < 4; ++nt)
                acc[mt][nt] = __builtin_amdgcn_mfma_f32_16x16x32_f16(af[mt], bf[nt], acc[mt][nt], 0, 0, 0);
    }

    // LN partials: s1 = sum(y), s2 = sum(y^2), s3 = sum(y*gamma*w)
    int dbase = blockIdx.y * 128 + wc * 64;
    float gw[4];
#pragma unroll
    for (int nt = 0; nt < 4; ++nt) {
        int d = dbase + nt*16 + lr;
        gw[nt] = gamma[d] * w_out[d];
    }
    int tbase = b * SEQ + c0 + blockIdx.x * 128 + wr * 64;
#pragma unroll
    for (int mt = 0; mt < 4; ++mt)
#pragma unroll
        for (int q = 0; q < 4; ++q) {
            float s1 = 0.f, s2 = 0.f, s3 = 0.f;
#pragma unroll
            for (int nt = 0; nt < 4; ++nt) {
                float y = acc[mt][nt][q];
                s1 += y; s2 += y * y; s3 += y * gw[nt];
            }
#pragma unroll
            for (int m = 1; m <= 8; m <<= 1) {
                s1 += __shfl_xor(s1, m);
                s2 += __shfl_xor(s2, m);
                s3 += __shfl_xor(s3, m);
            }
            if (lr == 0) {
                int t = tbase + mt*16 + lq*4 + q;
                atomicAdd(&part[t*4 + 0], s1);
                atomicAdd(&part[t*4 + 1], s2);
                atomicAdd(&part[t*4 + 2], s3);
            }
        }
}

// ---------------- finalize: LN + dot ----------------
__launch_bounds__(256)
__global__ void finalize_kernel(const float* __restrict__ part,
                                const float* __restrict__ gamma, const float* __restrict__ beta,
                                const float* __restrict__ w_out, const float* __restrict__ b_out,
                                float* __restrict__ out) {
    int tid = threadIdx.x;
    float gw = 0.f, bw = 0.f;
    for (int d = tid; d < DIM; d += 256) { gw += gamma[d] * w_out[d]; bw += beta[d] * w_out[d]; }
#pragma unroll
    for (int m = 1; m < 64; m <<= 1) { gw += __shfl_xor(gw, m); bw += __shfl_xor(bw, m); }
    __shared__ float red[8];
    if ((tid & 63) == 0) { red[(tid >> 6)*2] = gw; red[(tid >> 6)*2 + 1] = bw; }
    __syncthreads();
    float SGW = red[0] + red[2] + red[4] + red[6];
    float SBW = red[1] + red[3] + red[5] + red[7];
    int t = blockIdx.x * 256 + tid;
    float S1 = part[t*4], S2 = part[t*4 + 1], S3 = part[t*4 + 2];
    const float inv_d = 1.0f / 768.0f;
    float mu = S1 * inv_d;
    float var = S2 * inv_d - mu * mu;
    float rstd = rsqrtf(var + 1e-5f);
    out[t] = rstd * (S3 - mu * SGW) + SBW + b_out[0];
}

// ---------------- round-1 flash kernel (fallback if ws is small) ----------------
__launch_bounds__(512, 2)
__global__ void flash_kernel(const f16* __restrict__ Qh, const f16* __restrict__ Kh,
                             const f16* __restrict__ VT,
                             const float* __restrict__ gamma, const float* __restrict__ beta,
                             const float* __restrict__ w_out, const float* __restrict__ b_out,
                             float* __restrict__ out) {
    int tid = threadIdx.x;
    int w = tid >> 6, l = tid & 63;
    int r = w >> 1, c = w & 1;
    int lr = l & 15, lq = l >> 4;
    int b = blockIdx.y;
    int s0 = blockIdx.x * 64;

    __shared__ __attribute__((aligned(16))) float S_lds[64][40];
    __shared__ __attribute__((aligned(16))) f16  P_lds[64][40];
    __shared__ float row_m[64], row_l[64], row_scale[64];
    __shared__ float part[64][2][3];
    __shared__ float sgwred[2], sbwred[2];

    const f16* Qb = Qh + (size_t)(b * SEQ + s0) * DIM;
    const f16* Kb = Kh + (size_t)b * SEQ * DIM;
    const f16* Vb = VT + (size_t)b * DIM * SEQ;

    f16x8 qf[24];
    {
        const f16* qrow = Qb + (size_t)(r*16 + lr) * DIM + lq*8;
#pragma unroll
        for (int kc = 0; kc < 24; ++kc) qf[kc] = *(const f16x8*)(qrow + kc*32);
    }
    f32x4 acc[24] = {};
    if (tid < 64) { row_m[tid] = -INFINITY; row_l[tid] = 0.f; }
    __syncthreads();

    for (int kv0 = 0; kv0 < SEQ; kv0 += 32) {
        f32x4 s = {};
        const f16* krow = Kb + (size_t)(kv0 + c*16 + lr) * DIM + lq*8;
#pragma unroll
        for (int kc = 0; kc < 24; ++kc) {
            f16x8 kf = *(const f16x8*)(krow + kc*32);
            s = __builtin_amdgcn_mfma_f32_16x16x32_f16(qf[kc], kf, s, 0, 0, 0);
        }
        {
            int col = c*16 + lr;
            int rb = r*16 + lq*4;
#pragma unroll
            for (int q = 0; q < 4; ++q) S_lds[rb + q][col] = s[q];
        }
        __syncthreads();

        if (c == 0) {
            int row = r*16 + lr;
            const float4* p4 = (const float4*)&S_lds[row][lq*8];
            float4 v0 = p4[0], v1 = p4[1];
            float mx = fmaxf(fmaxf(fmaxf(v0.x, v0.y), fmaxf(v0.z, v0.w)),
                             fmaxf(fmaxf(v1.x, v1.y), fmaxf(v1.z, v1.w)));
            mx = fmaxf(mx, __shfl_xor(mx, 16));
            mx = fmaxf(mx, __shfl_xor(mx, 32));
            float m_old = row_m[row];
            float m_new = fmaxf(m_old, mx);
            float se = __expf(v0.x - m_new) + __expf(v0.y - m_new)
                     + __expf(v0.z - m_new) + __expf(v0.w - m_new)
                     + __expf(v1.x - m_new) + __expf(v1.y - m_new)
                     + __expf(v1.z - m_new) + __expf(v1.w - m_new);
            se += __shfl_xor(se, 16);
            se += __shfl_xor(se, 32);
            float scale = __expf(m_old - m_new);
            float l_new = row_l[row] * scale + se;
            if (lq == 0) { row_m[row] = m_new; row_l[row] = l_new; row_scale[row] = scale; }
        }
        __syncthreads();

        {
            int rb = r*16 + lq*4;
            float sc[4], mn[4];
#pragma unroll
            for (int q = 0; q < 4; ++q) { sc[q] = row_scale[rb+q]; mn[q] = row_m[rb+q]; }
#pragma unroll
            for (int q = 0; q < 4; ++q) {
                float p = __expf(s[q] - mn[q]);
                P_lds[rb+q][c*16 + lr] = (f16)p;
            }
#pragma unroll
            for (int nt = 0; nt < 24; ++nt)
#pragma unroll
                for (int q = 0; q < 4; ++q) acc[nt][q] *= sc[q];
        }
        __syncthreads();

        {
            f16x8 pa = *(const f16x8*)&P_lds[r*16 + lr][lq*8];
            const f16* vcol = Vb + (size_t)(c*384 + lr) * SEQ + kv0 + lq*8;
#pragma unroll
            for (int nt = 0; nt < 24; ++nt) {
                f16x8 vf = *(const f16x8*)(vcol + (size_t)nt * 16 * SEQ);
                acc[nt] = __builtin_amdgcn_mfma_f32_16x16x32_f16(pa, vf, acc[nt], 0, 0, 0);
            }
        }
    }

    int rb = r*16 + lq*4;
    float invl[4];
#pragma unroll
    for (int q = 0; q < 4; ++q) invl[q] = 1.0f / row_l[rb+q];
    float s1[4] = {0,0,0,0}, s2[4] = {0,0,0,0}, s3[4] = {0,0,0,0};
    float sgw = 0.f, sbw = 0.f;
#pragma unroll
    for (int nt = 0; nt < 24; ++nt) {
        int d = c*384 + nt*16 + lr;
        float g = gamma[d], wo = w_out[d], be = beta[d];
        float gwv = g * wo;
        sgw += gwv; sbw += be * wo;
#pragma unroll
        for (int q = 0; q < 4; ++q) {
            float y = acc[nt][q] * invl[q];
            s1[q] += y; s2[q] += y * y; s3[q] += y * gwv;
        }
    }
#pragma unroll
    for (int mask = 1; mask <= 8; mask <<= 1) {
#pragma unroll
        for (int q = 0; q < 4; ++q) {
            s1[q] += __shfl_xor(s1[q], mask);
            s2[q] += __shfl_xor(s2[q], mask);
            s3[q] += __shfl_xor(s3[q], mask);
        }
        sgw += __shfl_xor(sgw, mask);
        sbw += __shfl_xor(sbw, mask);
    }
    if (lr == 0) {
#pragma unroll
        for (int q = 0; q < 4; ++q) {
            part[rb+q][c][0] = s1[q];
            part[rb+q][c][1] = s2[q];
            part[rb+q][c][2] = s3[q];
        }
        if (r == 0 && lq == 0) { sgwred[c] = sgw; sbwred[c] = sbw; }
    }
    __syncthreads();
    if (tid < 64) {
        int row = tid;
        float S1 = part[row][0][0] + part[row][1][0];
        float S2 = part[row][0][1] + part[row][1][1];
        float S3 = part[row][0][2] + part[row][1][2];
        float SGW = sgwred[0] + sgwred[1];
        float SBW = sbwred[0] + sbwred[1];
        const float inv_d = 1.0f / 768.0f;
        float mu = S1 * inv_d;
        float var = S2 * inv_d - mu * mu;
        float rstd = rsqrtf(var + 1e-5f);
        float o = rstd * (S3 - mu * SGW) + SBW + b_out[0];
        out[(size_t)b * SEQ + s0 + row] = o;
    }
}

// ---------------- launch ----------------
extern "C" void kernel_launch(void* const* d_in, const int* in_sizes, int n_in,
                              void* d_out, int out_size, void* d_ws, size_t ws_size,
                              hipStream_t stream) {
    const float* x     = (const float*)d_in[0];
    const float* Wq    = (const float*)d_in[1];
    const float* bq    = (const float*)d_in[2];
    const float* Wk    = (const float*)d_in[3];
    const float* bk    = (const float*)d_in[4];
    const float* Wv    = (const float*)d_in[5];
    const float* bv    = (const float*)d_in[6];
    const float* gamma = (const float*)d_in[7];
    const float* beta  = (const float*)d_in[8];
    const float* w_out = (const float*)d_in[9];
    const float* b_out = (const float*)d_in[10];
    float* out = (float*)d_out;
    char* ws = (char*)d_ws;

    // fast-path layout
    const size_t OFF_Q    = 0;           // 25165824
    const size_t OFF_K    = 25165824;    // 25165824
    const size_t OFF_VT   = 50331648;    // 25165824
    const size_t OFF_S    = 75497472;    // 33554432 (xh overlaps here pre-proj)
    const size_t OFF_WH   = 109051904;   // 3538944
    const size_t OFF_PART = 112590848;   // 262144
    const size_t NEEDED_FAST = 112852992;

    if (ws_size >= NEEDED_FAST) {
        f16* Qh = (f16*)(ws + OFF_Q);
        f16* Kh = (f16*)(ws + OFF_K);
        f16* VT = (f16*)(ws + OFF_VT);
        f16* Sc = (f16*)(ws + OFF_S);
        f16* xh = (f16*)(ws + OFF_S);    // dead after proj_fast
        f16* Wh = (f16*)(ws + OFF_WH);
        float* part = (float*)(ws + OFF_PART);

        zero_kernel<<<256, 256, 0, stream>>>(part, 65536);
        cvt_kernel<<<2048, 256, 0, stream>>>(x, xh, TOK * DIM / 4);
        cvt_kernel<<<512, 256, 0, stream>>>(Wq, Wh,               DIM * DIM / 4);
        cvt_kernel<<<512, 256, 0, stream>>>(Wk, Wh + DIM * DIM,   DIM * DIM / 4);
        cvt_kernel<<<512, 256, 0, stream>>>(Wv, Wh + 2*DIM*DIM,   DIM * DIM / 4);

        proj_fast<<<dim3(TOK/128, 3*DIM/128), 256, 0, stream>>>(xh, Wh, bq, bk, bv, Qh, Kh, VT);

        for (int c = 0; c < NCHUNK; ++c) {
            int c0 = c * CH;
            qkt_kernel<<<dim3(CH/128, SEQ/128, BATCH), 256, 0, stream>>>(Qh, Kh, Sc, c0);
            softmax_kernel<<<BATCH * CH, 256, 0, stream>>>(Sc);
            pv_kernel<<<dim3(CH/128, DIM/128, BATCH), 256, 0, stream>>>(Sc, VT, gamma, w_out, part, c0);
        }
        finalize_kernel<<<TOK/256, 256, 0, stream>>>(part, gamma, beta, w_out, b_out, out);
    } else {
        // fallback: round-1 proven path (needs 104202240 B)
        if (ws_size < 104202240) return;
        f16* xh = (f16*)(ws);
        f16* Wh = (f16*)(ws + 25165824);
        f16* Qh = (f16*)(ws + 28704768);
        f16* Kh = (f16*)(ws + 53870592);
        f16* VT = (f16*)(ws + 79036416);

        cvt_kernel<<<2048, 256, 0, stream>>>(x, xh, TOK * DIM / 4);
        cvt_kernel<<<512, 256, 0, stream>>>(Wq, Wh,               DIM * DIM / 4);
        cvt_kernel<<<512, 256, 0, stream>>>(Wk, Wh + DIM * DIM,   DIM * DIM / 4);
        cvt_kernel<<<512, 256, 0, stream>>>(Wv, Wh + 2*DIM*DIM,   DIM * DIM / 4);

        proj_fast<<<dim3(TOK/128, 3*DIM/128), 256, 0, stream>>>(xh, Wh, bq, bk, bv, Qh, Kh, VT);
        flash_kernel<<<dim3(SEQ/64, BATCH), 512, 0, stream>>>(Qh, Kh, VT, gamma, beta, w_out, b_out, out);
    }
}

// Round 3
// 554.585 us; speedup vs baseline: 3.0595x; 1.2117x over previous
//
#include <hip/hip_runtime.h>
#include <math.h>
#include <stdint.h>

#define DIM 768
#define SEQ 4096
#define BATCH 4
#define TOK (BATCH*SEQ)

typedef _Float16 f16;
typedef _Float16 f16x8 __attribute__((ext_vector_type(8)));
typedef _Float16 f16x4 __attribute__((ext_vector_type(4)));
typedef float f32x4 __attribute__((ext_vector_type(4)));

// async global->LDS, 16B per lane; LDS dest is wave-uniform base + lane*16
#define GLOAD16(gp, lp) __builtin_amdgcn_global_load_lds( \
    (const __attribute__((address_space(1))) unsigned int*)(gp), \
    (__attribute__((address_space(3))) unsigned int*)(lp), 16, 0, 0)

// ---------------- fp32 -> fp16 convert ----------------
__global__ void cvt_kernel(const float* __restrict__ src, f16* __restrict__ dst, int n4) {
    int i = blockIdx.x * blockDim.x + threadIdx.x;
    int stride = gridDim.x * blockDim.x;
    for (; i < n4; i += stride) {
        float4 v = ((const float4*)src)[i];
        f16x4 h = { (f16)v.x, (f16)v.y, (f16)v.z, (f16)v.w };
        ((f16x4*)dst)[i] = h;
    }
}

__global__ void zero_kernel(float* __restrict__ p, int n) {
    int i = blockIdx.x * blockDim.x + threadIdx.x;
    if (i < n) p[i] = 0.f;
}

// ---------------- QKV projection GEMM, repacked coalesced epilogue ----------------
// Y[t][e] = sum_d xh[t][d]*Wh[e][d] + bias;  M=16384, N=2304 (Q|K|V), K=768
__launch_bounds__(256, 2)
__global__ void proj_kernel3(const f16* __restrict__ xh, const f16* __restrict__ Wh,
                             const float* __restrict__ bq, const float* __restrict__ bk,
                             const float* __restrict__ bv,
                             f16* __restrict__ Qh, f16* __restrict__ Kh,
                             f16* __restrict__ Vd, int vscatter) {
    __shared__ __align__(16) char lds[17408];
    f16* As = (f16*)lds;                 // [128*32]
    f16* Bs = (f16*)(lds + 8192);        // [128*32]
    typedef f16 repRow[136];
    repRow* rep = (repRow*)lds;          // [64][136] (reused after K-loop)

    int tid = threadIdx.x;
    int w = tid >> 6, l = tid & 63;
    int wr = w >> 1, wc = w & 1;
    int lr = l & 15, lq = l >> 4;
    int srow = l >> 2, skg = (l & 3) * 8;

    const f16* Abase = xh + (size_t)blockIdx.x * 128 * DIM;
    const f16* Bbase = Wh + (size_t)blockIdx.y * 128 * DIM;

    f32x4 acc[4][4] = {};
    for (int k0 = 0; k0 < DIM; k0 += 32) {
        __syncthreads();
        GLOAD16(Abase + (size_t)(w*16 + srow)*DIM + k0 + skg,     As + w*512);
        GLOAD16(Abase + (size_t)((4+w)*16 + srow)*DIM + k0 + skg, As + (4+w)*512);
        GLOAD16(Bbase + (size_t)(w*16 + srow)*DIM + k0 + skg,     Bs + w*512);
        GLOAD16(Bbase + (size_t)((4+w)*16 + srow)*DIM + k0 + skg, Bs + (4+w)*512);
        __syncthreads();
        f16x8 af[4], bf[4];
#pragma unroll
        for (int mt = 0; mt < 4; ++mt) af[mt] = *(const f16x8*)&As[(wr*64 + mt*16 + lr)*32 + lq*8];
#pragma unroll
        for (int nt = 0; nt < 4; ++nt) bf[nt] = *(const f16x8*)&Bs[(wc*64 + nt*16 + lr)*32 + lq*8];
#pragma unroll
        for (int mt = 0; mt < 4; ++mt)
#pragma unroll
            for (int nt = 0; nt < 4; ++nt)
                acc[mt][nt] = __builtin_amdgcn_mfma_f32_16x16x32_f16(af[mt], bf[nt], acc[mt][nt], 0, 0, 0);
    }

    int mat = blockIdx.y / 6;                 // 0=Q,1=K,2=V (uniform per block)
    int e0  = (blockIdx.y - mat*6) * 128;
    const float* bias = (mat == 0) ? bq : ((mat == 1) ? bk : bv);
    float be[4];
#pragma unroll
    for (int nt = 0; nt < 4; ++nt) be[nt] = bias[e0 + wc*64 + nt*16 + lr];

    int trow0 = blockIdx.x * 128;

    if (mat == 2 && vscatter) {
        // fallback tier: scatter directly into VT[(b*DIM+e)*SEQ + t]
#pragma unroll
        for (int nt = 0; nt < 4; ++nt) {
            int e = e0 + wc*64 + nt*16 + lr;
#pragma unroll
            for (int mt = 0; mt < 4; ++mt)
#pragma unroll
                for (int q = 0; q < 4; ++q) {
                    int t = trow0 + wr*64 + mt*16 + lq*4 + q;
                    Vd[((size_t)(t >> 12) * DIM + e) * SEQ + (t & (SEQ - 1))] =
                        (f16)(acc[mt][nt][q] + be[nt]);
                }
        }
        return;
    }

    f16* dst = (mat == 0) ? Qh : ((mat == 1) ? Kh : Vd);   // all row-major [t][DIM]
#pragma unroll
    for (int ph = 0; ph < 2; ++ph) {
        __syncthreads();
        if (wr == ph) {
#pragma unroll
            for (int mt = 0; mt < 4; ++mt)
#pragma unroll
                for (int nt = 0; nt < 4; ++nt)
#pragma unroll
                    for (int q = 0; q < 4; ++q)
                        rep[mt*16 + lq*4 + q][wc*64 + nt*16 + lr] = (f16)(acc[mt][nt][q] + be[nt]);
        }
        __syncthreads();
        int row = tid >> 2, cg = (tid & 3) * 4;
        f16* drow = dst + (size_t)(trow0 + ph*64 + row) * DIM + e0;
        const f16* srcr = rep[row];
#pragma unroll
        for (int j = 0; j < 4; ++j)
            *(f16x8*)(drow + (cg + j)*8) = *(const f16x8*)(srcr + (cg + j)*8);
    }
}

// ---------------- V row-major -> VT transpose (64x64 LDS tiles) ----------------
__launch_bounds__(256)
__global__ void transpose_v(const f16* __restrict__ Vr, f16* __restrict__ VT) {
    __shared__ f16 t[64][72];
    int tid = threadIdx.x;
    int b = blockIdx.z, s0 = blockIdx.x * 64, d0 = blockIdx.y * 64;
    int r = tid >> 2, c4 = tid & 3;
    const f16* src = Vr + ((size_t)b * SEQ + s0 + r) * DIM + d0;
    *(f16x8*)&t[r][c4*8]     = *(const f16x8*)(src + c4*8);
    *(f16x8*)&t[r][(c4+4)*8] = *(const f16x8*)(src + (c4+4)*8);
    __syncthreads();
    int rd = tid >> 2;
    f16* dst = VT + ((size_t)b * DIM + d0 + rd) * SEQ + s0;
#pragma unroll
    for (int c = c4; c < 8; c += 4) {
        f16x8 v;
#pragma unroll
        for (int j = 0; j < 8; ++j) v[j] = t[c*8 + j][rd];
        *(f16x8*)(dst + c*8) = v;
    }
}

// ---------------- S = Q K^T for one chunk (fp16, repacked coalesced store) ----------------
__launch_bounds__(256, 2)
__global__ void qkt_kernel3(const f16* __restrict__ Qh, const f16* __restrict__ Kh,
                            f16* __restrict__ Sc, int c0, int ch) {
    __shared__ __align__(16) char lds[17408];
    f16* As = (f16*)lds;
    f16* Bs = (f16*)(lds + 8192);
    typedef f16 repRow[136];
    repRow* rep = (repRow*)lds;

    int tid = threadIdx.x;
    int w = tid >> 6, l = tid & 63;
    int wr = w >> 1, wc = w & 1;
    int lr = l & 15, lq = l >> 4;
    int srow = l >> 2, skg = (l & 3) * 8;
    int b = blockIdx.z;

    const f16* Abase = Qh + ((size_t)b * SEQ + c0 + blockIdx.x * 128) * DIM;
    const f16* Bbase = Kh + (size_t)b * SEQ * DIM + (size_t)blockIdx.y * 128 * DIM;

    f32x4 acc[4][4] = {};
    for (int k0 = 0; k0 < DIM; k0 += 32) {
        __syncthreads();
        GLOAD16(Abase + (size_t)(w*16 + srow)*DIM + k0 + skg,     As + w*512);
        GLOAD16(Abase + (size_t)((4+w)*16 + srow)*DIM + k0 + skg, As + (4+w)*512);
        GLOAD16(Bbase + (size_t)(w*16 + srow)*DIM + k0 + skg,     Bs + w*512);
        GLOAD16(Bbase + (size_t)((4+w)*16 + srow)*DIM + k0 + skg, Bs + (4+w)*512);
        __syncthreads();
        f16x8 af[4], bf[4];
#pragma unroll
        for (int mt = 0; mt < 4; ++mt) af[mt] = *(const f16x8*)&As[(wr*64 + mt*16 + lr)*32 + lq*8];
#pragma unroll
        for (int nt = 0; nt < 4; ++nt) bf[nt] = *(const f16x8*)&Bs[(wc*64 + nt*16 + lr)*32 + lq*8];
#pragma unroll
        for (int mt = 0; mt < 4; ++mt)
#pragma unroll
            for (int nt = 0; nt < 4; ++nt)
                acc[mt][nt] = __builtin_amdgcn_mfma_f32_16x16x32_f16(af[mt], bf[nt], acc[mt][nt], 0, 0, 0);
    }

    size_t rowbase = (size_t)b * ch + blockIdx.x * 128;
    int col0 = blockIdx.y * 128;
#pragma unroll
    for (int ph = 0; ph < 2; ++ph) {
        __syncthreads();
        if (wr == ph) {
#pragma unroll
            for (int mt = 0; mt < 4; ++mt)
#pragma unroll
                for (int nt = 0; nt < 4; ++nt)
#pragma unroll
                    for (int q = 0; q < 4; ++q)
                        rep[mt*16 + lq*4 + q][wc*64 + nt*16 + lr] = (f16)acc[mt][nt][q];
        }
        __syncthreads();
        int row = tid >> 2, cg = (tid & 3) * 4;
        f16* drow = Sc + (rowbase + ph*64 + row) * SEQ + col0;
        const f16* srcr = rep[row];
#pragma unroll
        for (int j = 0; j < 4; ++j)
            *(f16x8*)(drow + (cg + j)*8) = *(const f16x8*)(srcr + (cg + j)*8);
    }
}

// ---------------- in-place row softmax (normalized P, fp16) ----------------
__launch_bounds__(256, 4)
__global__ void softmax_kernel(f16* __restrict__ S) {
    int tid = threadIdx.x;
    size_t row = blockIdx.x;
    f16* p = S + row * SEQ + tid * 16;
    f16x8 v0 = ((const f16x8*)p)[0];
    f16x8 v1 = ((const f16x8*)p)[1];
    float x[16];
#pragma unroll
    for (int i = 0; i < 8; ++i) { x[i] = (float)v0[i]; x[8+i] = (float)v1[i]; }
    float mx = x[0];
#pragma unroll
    for (int i = 1; i < 16; ++i) mx = fmaxf(mx, x[i]);
#pragma unroll
    for (int m = 1; m <= 32; m <<= 1) mx = fmaxf(mx, __shfl_xor(mx, m));
    __shared__ float redm[4], redl[4];
    int w = tid >> 6;
    if ((tid & 63) == 0) redm[w] = mx;
    __syncthreads();
    mx = fmaxf(fmaxf(redm[0], redm[1]), fmaxf(redm[2], redm[3]));
    float e[16]; float se = 0.f;
#pragma unroll
    for (int i = 0; i < 16; ++i) { e[i] = __expf(x[i] - mx); se += e[i]; }
#pragma unroll
    for (int m = 1; m <= 32; m <<= 1) se += __shfl_xor(se, m);
    if ((tid & 63) == 0) redl[w] = se;
    __syncthreads();
    float inv = 1.0f / (redl[0] + redl[1] + redl[2] + redl[3]);
    f16x8 o0, o1;
#pragma unroll
    for (int i = 0; i < 8; ++i) { o0[i] = (f16)(e[i] * inv); o1[i] = (f16)(e[8+i] * inv); }
    ((f16x8*)p)[0] = o0;
    ((f16x8*)p)[1] = o1;
}

// ---------------- O = P * V^T (128x64 tiles) + fused LN-partial epilogue ----------------
__launch_bounds__(256, 2)
__global__ void pv_kernel3(const f16* __restrict__ P, const f16* __restrict__ VT,
                           const float* __restrict__ gamma, const float* __restrict__ w_out,
                           float* __restrict__ part, int c0, int ch) {
    __shared__ f16 As[128*32];   // P tile
    __shared__ f16 Bs[64*32];    // VT tile
    int tid = threadIdx.x;
    int w = tid >> 6, l = tid & 63;
    int wr = w >> 1, wc = w & 1;
    int lr = l & 15, lq = l >> 4;
    int srow = l >> 2, skg = (l & 3) * 8;
    int b = blockIdx.z;

    const f16* Abase = P  + ((size_t)b * ch + blockIdx.x * 128) * SEQ;
    const f16* Bbase = VT + (size_t)b * DIM * SEQ + (size_t)blockIdx.y * 64 * SEQ;

    f32x4 acc[4][2] = {};
    for (int k0 = 0; k0 < SEQ; k0 += 32) {
        __syncthreads();
        GLOAD16(Abase + (size_t)(w*16 + srow)*SEQ + k0 + skg,     As + w*512);
        GLOAD16(Abase + (size_t)((4+w)*16 + srow)*SEQ + k0 + skg, As + (4+w)*512);
        GLOAD16(Bbase + (size_t)(w*16 + srow)*SEQ + k0 + skg,     Bs + w*512);
        __syncthreads();
        f16x8 af[4], bf[2];
#pragma unroll
        for (int mt = 0; mt < 4; ++mt) af[mt] = *(const f16x8*)&As[(wr*64 + mt*16 + lr)*32 + lq*8];
#pragma unroll
        for (int nt = 0; nt < 2; ++nt) bf[nt] = *(const f16x8*)&Bs[(wc*32 + nt*16 + lr)*32 + lq*8];
#pragma unroll
        for (int mt = 0; mt < 4; ++mt)
#pragma unroll
            for (int nt = 0; nt < 2; ++nt)
                acc[mt][nt] = __builtin_amdgcn_mfma_f32_16x16x32_f16(af[mt], bf[nt], acc[mt][nt], 0, 0, 0);
    }

    // LN partials: s1=sum(y), s2=sum(y^2), s3=sum(y*gamma*w)
    float gw[2];
#pragma unroll
    for (int nt = 0; nt < 2; ++nt) {
        int d = blockIdx.y * 64 + wc*32 + nt*16 + lr;
        gw[nt] = gamma[d] * w_out[d];
    }
    int tbase = b * SEQ + c0 + blockIdx.x * 128 + wr * 64;
#pragma unroll
    for (int mt = 0; mt < 4; ++mt)
#pragma unroll
        for (int q = 0; q < 4; ++q) {
            float s1 = 0.f, s2 = 0.f, s3 = 0.f;
#pragma unroll
            for (int nt = 0; nt < 2; ++nt) {
                float y = acc[mt][nt][q];
                s1 += y; s2 += y * y; s3 += y * gw[nt];
            }
#pragma unroll
            for (int m = 1; m <= 8; m <<= 1) {
                s1 += __shfl_xor(s1, m);
                s2 += __shfl_xor(s2, m);
                s3 += __shfl_xor(s3, m);
            }
            if (lr == 0) {
                int t = tbase + mt*16 + lq*4 + q;
                atomicAdd(&part[t*4 + 0], s1);
                atomicAdd(&part[t*4 + 1], s2);
                atomicAdd(&part[t*4 + 2], s3);
            }
        }
}

// ---------------- finalize: LN + dot ----------------
__launch_bounds__(256)
__global__ void finalize_kernel(const float* __restrict__ part,
                                const float* __restrict__ gamma, const float* __restrict__ beta,
                                const float* __restrict__ w_out, const float* __restrict__ b_out,
                                float* __restrict__ out) {
    int tid = threadIdx.x;
    float gw = 0.f, bw = 0.f;
    for (int d = tid; d < DIM; d += 256) { gw += gamma[d] * w_out[d]; bw += beta[d] * w_out[d]; }
#pragma unroll
    for (int m = 1; m < 64; m <<= 1) { gw += __shfl_xor(gw, m); bw += __shfl_xor(bw, m); }
    __shared__ float red[8];
    if ((tid & 63) == 0) { red[(tid >> 6)*2] = gw; red[(tid >> 6)*2 + 1] = bw; }
    __syncthreads();
    float SGW = red[0] + red[2] + red[4] + red[6];
    float SBW = red[1] + red[3] + red[5] + red[7];
    int t = blockIdx.x * 256 + tid;
    float S1 = part[t*4], S2 = part[t*4 + 1], S3 = part[t*4 + 2];
    const float inv_d = 1.0f / 768.0f;
    float mu = S1 * inv_d;
    float var = S2 * inv_d - mu * mu;
    float rstd = rsqrtf(var + 1e-5f);
    out[t] = rstd * (S3 - mu * SGW) + SBW + b_out[0];
}

// ---------------- launch ----------------
extern "C" void kernel_launch(void* const* d_in, const int* in_sizes, int n_in,
                              void* d_out, int out_size, void* d_ws, size_t ws_size,
                              hipStream_t stream) {
    const float* x     = (const float*)d_in[0];
    const float* Wq    = (const float*)d_in[1];
    const float* bq    = (const float*)d_in[2];
    const float* Wk    = (const float*)d_in[3];
    const float* bk    = (const float*)d_in[4];
    const float* Wv    = (const float*)d_in[5];
    const float* bv    = (const float*)d_in[6];
    const float* gamma = (const float*)d_in[7];
    const float* beta  = (const float*)d_in[8];
    const float* w_out = (const float*)d_in[9];
    const float* b_out = (const float*)d_in[10];
    float* out = (float*)d_out;
    char* ws = (char*)d_ws;

    const size_t SZM  = 25165824;        // one 16384x768 f16 matrix
    const size_t BASE = 3 * SZM;         // after Qh|Kh|VT = 75497472
    f16* Qh = (f16*)(ws);
    f16* Kh = (f16*)(ws + SZM);
    f16* VT = (f16*)(ws + 2*SZM);

    // tier selection
    int ch; int vscatter; size_t off_wh;
    f16 *xh, *Vr, *Sc;
    const size_t NEED_A = BASE + 67108864 + 3538944 + 262144;   // 146407424, CH=2048
    const size_t NEED_B = BASE + 33554432 + SZM + 3538944 + 262144; // 138018816, CH=1024 + Vr
    const size_t NEED_C = BASE + 33554432 + 3538944 + 262144;   // 112852992, CH=1024 scatter (proven)

    if (ws_size >= NEED_A) {
        ch = 2048; vscatter = 0;
        Sc = (f16*)(ws + BASE);
        xh = (f16*)(ws + BASE);              // dead before qkt chunk 0
        Vr = (f16*)(ws + BASE + SZM);        // dead after transpose
        off_wh = BASE + 67108864;
    } else if (ws_size >= NEED_B) {
        ch = 1024; vscatter = 0;
        Sc = (f16*)(ws + BASE);
        xh = (f16*)(ws + BASE);
        Vr = (f16*)(ws + BASE + 33554432);
        off_wh = BASE + 33554432 + SZM;
    } else if (ws_size >= NEED_C) {
        ch = 1024; vscatter = 1;
        Sc = (f16*)(ws + BASE);
        xh = (f16*)(ws + BASE);
        Vr = VT;                              // proj scatters straight into VT
        off_wh = BASE + 33554432;
    } else {
        return;  // insufficient workspace: leave output poisoned (visible failure)
    }
    f16* Wh = (f16*)(ws + off_wh);
    float* part = (float*)(ws + off_wh + 3538944);

    zero_kernel<<<256, 256, 0, stream>>>(part, 65536);
    cvt_kernel<<<2048, 256, 0, stream>>>(x, xh, TOK * DIM / 4);
    cvt_kernel<<<512, 256, 0, stream>>>(Wq, Wh,               DIM * DIM / 4);
    cvt_kernel<<<512, 256, 0, stream>>>(Wk, Wh + DIM * DIM,   DIM * DIM / 4);
    cvt_kernel<<<512, 256, 0, stream>>>(Wv, Wh + 2*DIM*DIM,   DIM * DIM / 4);

    proj_kernel3<<<dim3(TOK/128, 18), 256, 0, stream>>>(xh, Wh, bq, bk, bv, Qh, Kh, Vr, vscatter);
    if (!vscatter)
        transpose_v<<<dim3(SEQ/64, DIM/64, BATCH), 256, 0, stream>>>(Vr, VT);

    int nch = SEQ / ch;
    for (int c = 0; c < nch; ++c) {
        int c0 = c * ch;
        qkt_kernel3<<<dim3(ch/128, SEQ/128, BATCH), 256, 0, stream>>>(Qh, Kh, Sc, c0, ch);
        softmax_kernel<<<BATCH * ch, 256, 0, stream>>>(Sc);
        pv_kernel3<<<dim3(ch/128, DIM/64, BATCH), 256, 0, stream>>>(Sc, VT, gamma, w_out, part, c0, ch);
    }
    finalize_kernel<<<TOK/256, 256, 0, stream>>>(part, gamma, beta, w_out, b_out, out);
}

// Round 4
// 479.982 us; speedup vs baseline: 3.5350x; 1.1554x over previous
//
#include <hip/hip_runtime.h>
#include <math.h>
#include <stdint.h>

#define DIM 768
#define SEQ 4096
#define BATCH 4
#define TOK (BATCH*SEQ)

typedef _Float16 f16;
typedef _Float16 f16x8 __attribute__((ext_vector_type(8)));
typedef _Float16 f16x4 __attribute__((ext_vector_type(4)));
typedef float f32x4 __attribute__((ext_vector_type(4)));

// async global->LDS, 16B per lane; LDS dest is wave-uniform base + lane*16
#define GLOAD16(gp, lp) __builtin_amdgcn_global_load_lds( \
    (const __attribute__((address_space(1))) unsigned int*)(gp), \
    (__attribute__((address_space(3))) unsigned int*)(lp), 16, 0, 0)

// ---------------- fp32 -> fp16 convert ----------------
__global__ void cvt_kernel(const float* __restrict__ src, f16* __restrict__ dst, int n4) {
    int i = blockIdx.x * blockDim.x + threadIdx.x;
    int stride = gridDim.x * blockDim.x;
    for (; i < n4; i += stride) {
        float4 v = ((const float4*)src)[i];
        f16x4 h = { (f16)v.x, (f16)v.y, (f16)v.z, (f16)v.w };
        ((f16x4*)dst)[i] = h;
    }
}

__global__ void zero_kernel(float* __restrict__ p, int n) {
    int i = blockIdx.x * blockDim.x + threadIdx.x;
    if (i < n) p[i] = 0.f;
}

// ---------------- QKV projection GEMM (BK=64 as two 32-subtiles / barrier) ----------------
__launch_bounds__(256, 3)
__global__ void proj_kernel4(const f16* __restrict__ xh, const f16* __restrict__ Wh,
                             const float* __restrict__ bq, const float* __restrict__ bk,
                             const float* __restrict__ bv,
                             f16* __restrict__ Qh, f16* __restrict__ Kh,
                             f16* __restrict__ Vd, int vscatter) {
    __shared__ __align__(16) char lds[32768];
    f16* As0 = (f16*)lds;
    f16* As1 = (f16*)(lds + 8192);
    f16* Bs0 = (f16*)(lds + 16384);
    f16* Bs1 = (f16*)(lds + 24576);
    typedef f16 repRow[136];
    repRow* rep = (repRow*)lds;          // epilogue reuse (17408 B < 32768 B)

    int tid = threadIdx.x;
    int w = tid >> 6, l = tid & 63;
    int wr = w >> 1, wc = w & 1;
    int lr = l & 15, lq = l >> 4;
    int srow = l >> 2, skg = (l & 3) * 8;

    const f16* Abase = xh + (size_t)blockIdx.x * 128 * DIM;
    const f16* Bbase = Wh + (size_t)blockIdx.y * 128 * DIM;

    f32x4 acc[4][4] = {};
    for (int k0 = 0; k0 < DIM; k0 += 64) {
        __syncthreads();
        GLOAD16(Abase + (size_t)(w*16 + srow)*DIM + k0 + skg,          As0 + w*512);
        GLOAD16(Abase + (size_t)((4+w)*16 + srow)*DIM + k0 + skg,      As0 + (4+w)*512);
        GLOAD16(Abase + (size_t)(w*16 + srow)*DIM + k0 + 32 + skg,     As1 + w*512);
        GLOAD16(Abase + (size_t)((4+w)*16 + srow)*DIM + k0 + 32 + skg, As1 + (4+w)*512);
        GLOAD16(Bbase + (size_t)(w*16 + srow)*DIM + k0 + skg,          Bs0 + w*512);
        GLOAD16(Bbase + (size_t)((4+w)*16 + srow)*DIM + k0 + skg,      Bs0 + (4+w)*512);
        GLOAD16(Bbase + (size_t)(w*16 + srow)*DIM + k0 + 32 + skg,     Bs1 + w*512);
        GLOAD16(Bbase + (size_t)((4+w)*16 + srow)*DIM + k0 + 32 + skg, Bs1 + (4+w)*512);
        __syncthreads();
        f16x8 a0[4], b0[4], a1[4], b1[4];
#pragma unroll
        for (int mt = 0; mt < 4; ++mt) {
            a0[mt] = *(const f16x8*)&As0[(wr*64 + mt*16 + lr)*32 + lq*8];
            a1[mt] = *(const f16x8*)&As1[(wr*64 + mt*16 + lr)*32 + lq*8];
        }
#pragma unroll
        for (int nt = 0; nt < 4; ++nt) {
            b0[nt] = *(const f16x8*)&Bs0[(wc*64 + nt*16 + lr)*32 + lq*8];
            b1[nt] = *(const f16x8*)&Bs1[(wc*64 + nt*16 + lr)*32 + lq*8];
        }
#pragma unroll
        for (int mt = 0; mt < 4; ++mt)
#pragma unroll
            for (int nt = 0; nt < 4; ++nt) {
                acc[mt][nt] = __builtin_amdgcn_mfma_f32_16x16x32_f16(a0[mt], b0[nt], acc[mt][nt], 0, 0, 0);
                acc[mt][nt] = __builtin_amdgcn_mfma_f32_16x16x32_f16(a1[mt], b1[nt], acc[mt][nt], 0, 0, 0);
            }
    }

    int mat = blockIdx.y / 6;                 // 0=Q,1=K,2=V (uniform per block)
    int e0  = (blockIdx.y - mat*6) * 128;
    const float* bias = (mat == 0) ? bq : ((mat == 1) ? bk : bv);
    float be[4];
#pragma unroll
    for (int nt = 0; nt < 4; ++nt) be[nt] = bias[e0 + wc*64 + nt*16 + lr];

    int trow0 = blockIdx.x * 128;

    if (mat == 2 && vscatter) {
#pragma unroll
        for (int nt = 0; nt < 4; ++nt) {
            int e = e0 + wc*64 + nt*16 + lr;
#pragma unroll
            for (int mt = 0; mt < 4; ++mt)
#pragma unroll
                for (int q = 0; q < 4; ++q) {
                    int t = trow0 + wr*64 + mt*16 + lq*4 + q;
                    Vd[((size_t)(t >> 12) * DIM + e) * SEQ + (t & (SEQ - 1))] =
                        (f16)(acc[mt][nt][q] + be[nt]);
                }
        }
        return;
    }

    f16* dst = (mat == 0) ? Qh : ((mat == 1) ? Kh : Vd);   // row-major [t][DIM]
#pragma unroll
    for (int ph = 0; ph < 2; ++ph) {
        __syncthreads();
        if (wr == ph) {
#pragma unroll
            for (int mt = 0; mt < 4; ++mt)
#pragma unroll
                for (int nt = 0; nt < 4; ++nt)
#pragma unroll
                    for (int q = 0; q < 4; ++q)
                        rep[mt*16 + lq*4 + q][wc*64 + nt*16 + lr] = (f16)(acc[mt][nt][q] + be[nt]);
        }
        __syncthreads();
        int row = tid >> 2, cg = (tid & 3) * 4;
        f16* drow = dst + (size_t)(trow0 + ph*64 + row) * DIM + e0;
        const f16* srcr = rep[row];
#pragma unroll
        for (int j = 0; j < 4; ++j)
            *(f16x8*)(drow + (cg + j)*8) = *(const f16x8*)(srcr + (cg + j)*8);
    }
}

// ---------------- V row-major -> VT transpose (64x64 LDS tiles) ----------------
__launch_bounds__(256)
__global__ void transpose_v(const f16* __restrict__ Vr, f16* __restrict__ VT) {
    __shared__ f16 t[64][72];
    int tid = threadIdx.x;
    int b = blockIdx.z, s0 = blockIdx.x * 64, d0 = blockIdx.y * 64;
    int r = tid >> 2, c4 = tid & 3;
    const f16* src = Vr + ((size_t)b * SEQ + s0 + r) * DIM + d0;
    *(f16x8*)&t[r][c4*8]     = *(const f16x8*)(src + c4*8);
    *(f16x8*)&t[r][(c4+4)*8] = *(const f16x8*)(src + (c4+4)*8);
    __syncthreads();
    int rd = tid >> 2;
    f16* dst = VT + ((size_t)b * DIM + d0 + rd) * SEQ + s0;
#pragma unroll
    for (int c = c4; c < 8; c += 4) {
        f16x8 v;
#pragma unroll
        for (int j = 0; j < 8; ++j) v[j] = t[c*8 + j][rd];
        *(f16x8*)(dst + c*8) = v;
    }
}

// ---------------- S = Q K^T (BK=64 two-subtile, coalesced repack store) ----------------
__launch_bounds__(256, 3)
__global__ void qkt_kernel4(const f16* __restrict__ Qh, const f16* __restrict__ Kh,
                            f16* __restrict__ Sc, int c0, int ch) {
    __shared__ __align__(16) char lds[32768];
    f16* As0 = (f16*)lds;
    f16* As1 = (f16*)(lds + 8192);
    f16* Bs0 = (f16*)(lds + 16384);
    f16* Bs1 = (f16*)(lds + 24576);
    typedef f16 repRow[136];
    repRow* rep = (repRow*)lds;

    int tid = threadIdx.x;
    int w = tid >> 6, l = tid & 63;
    int wr = w >> 1, wc = w & 1;
    int lr = l & 15, lq = l >> 4;
    int srow = l >> 2, skg = (l & 3) * 8;
    int b = blockIdx.z;

    const f16* Abase = Qh + ((size_t)b * SEQ + c0 + blockIdx.x * 128) * DIM;
    const f16* Bbase = Kh + (size_t)b * SEQ * DIM + (size_t)blockIdx.y * 128 * DIM;

    f32x4 acc[4][4] = {};
    for (int k0 = 0; k0 < DIM; k0 += 64) {
        __syncthreads();
        GLOAD16(Abase + (size_t)(w*16 + srow)*DIM + k0 + skg,          As0 + w*512);
        GLOAD16(Abase + (size_t)((4+w)*16 + srow)*DIM + k0 + skg,      As0 + (4+w)*512);
        GLOAD16(Abase + (size_t)(w*16 + srow)*DIM + k0 + 32 + skg,     As1 + w*512);
        GLOAD16(Abase + (size_t)((4+w)*16 + srow)*DIM + k0 + 32 + skg, As1 + (4+w)*512);
        GLOAD16(Bbase + (size_t)(w*16 + srow)*DIM + k0 + skg,          Bs0 + w*512);
        GLOAD16(Bbase + (size_t)((4+w)*16 + srow)*DIM + k0 + skg,      Bs0 + (4+w)*512);
        GLOAD16(Bbase + (size_t)(w*16 + srow)*DIM + k0 + 32 + skg,     Bs1 + w*512);
        GLOAD16(Bbase + (size_t)((4+w)*16 + srow)*DIM + k0 + 32 + skg, Bs1 + (4+w)*512);
        __syncthreads();
        f16x8 a0[4], b0[4], a1[4], b1[4];
#pragma unroll
        for (int mt = 0; mt < 4; ++mt) {
            a0[mt] = *(const f16x8*)&As0[(wr*64 + mt*16 + lr)*32 + lq*8];
            a1[mt] = *(const f16x8*)&As1[(wr*64 + mt*16 + lr)*32 + lq*8];
        }
#pragma unroll
        for (int nt = 0; nt < 4; ++nt) {
            b0[nt] = *(const f16x8*)&Bs0[(wc*64 + nt*16 + lr)*32 + lq*8];
            b1[nt] = *(const f16x8*)&Bs1[(wc*64 + nt*16 + lr)*32 + lq*8];
        }
#pragma unroll
        for (int mt = 0; mt < 4; ++mt)
#pragma unroll
            for (int nt = 0; nt < 4; ++nt) {
                acc[mt][nt] = __builtin_amdgcn_mfma_f32_16x16x32_f16(a0[mt], b0[nt], acc[mt][nt], 0, 0, 0);
                acc[mt][nt] = __builtin_amdgcn_mfma_f32_16x16x32_f16(a1[mt], b1[nt], acc[mt][nt], 0, 0, 0);
            }
    }

    size_t rowbase = (size_t)b * ch + blockIdx.x * 128;
    int col0 = blockIdx.y * 128;
#pragma unroll
    for (int ph = 0; ph < 2; ++ph) {
        __syncthreads();
        if (wr == ph) {
#pragma unroll
            for (int mt = 0; mt < 4; ++mt)
#pragma unroll
                for (int nt = 0; nt < 4; ++nt)
#pragma unroll
                    for (int q = 0; q < 4; ++q)
                        rep[mt*16 + lq*4 + q][wc*64 + nt*16 + lr] = (f16)acc[mt][nt][q];
        }
        __syncthreads();
        int row = tid >> 2, cg = (tid & 3) * 4;
        f16* drow = Sc + (rowbase + ph*64 + row) * SEQ + col0;
        const f16* srcr = rep[row];
#pragma unroll
        for (int j = 0; j < 4; ++j)
            *(f16x8*)(drow + (cg + j)*8) = *(const f16x8*)(srcr + (cg + j)*8);
    }
}

// ---------------- in-place row softmax (normalized P, fp16) ----------------
__launch_bounds__(256, 4)
__global__ void softmax_kernel(f16* __restrict__ S) {
    int tid = threadIdx.x;
    size_t row = blockIdx.x;
    f16* p = S + row * SEQ + tid * 16;
    f16x8 v0 = ((const f16x8*)p)[0];
    f16x8 v1 = ((const f16x8*)p)[1];
    float x[16];
#pragma unroll
    for (int i = 0; i < 8; ++i) { x[i] = (float)v0[i]; x[8+i] = (float)v1[i]; }
    float mx = x[0];
#pragma unroll
    for (int i = 1; i < 16; ++i) mx = fmaxf(mx, x[i]);
#pragma unroll
    for (int m = 1; m <= 32; m <<= 1) mx = fmaxf(mx, __shfl_xor(mx, m));
    __shared__ float redm[4], redl[4];
    int w = tid >> 6;
    if ((tid & 63) == 0) redm[w] = mx;
    __syncthreads();
    mx = fmaxf(fmaxf(redm[0], redm[1]), fmaxf(redm[2], redm[3]));
    float e[16]; float se = 0.f;
#pragma unroll
    for (int i = 0; i < 16; ++i) { e[i] = __expf(x[i] - mx); se += e[i]; }
#pragma unroll
    for (int m = 1; m <= 32; m <<= 1) se += __shfl_xor(se, m);
    if ((tid & 63) == 0) redl[w] = se;
    __syncthreads();
    float inv = 1.0f / (redl[0] + redl[1] + redl[2] + redl[3]);
    f16x8 o0, o1;
#pragma unroll
    for (int i = 0; i < 8; ++i) { o0[i] = (f16)(e[i] * inv); o1[i] = (f16)(e[8+i] * inv); }
    ((f16x8*)p)[0] = o0;
    ((f16x8*)p)[1] = o1;
}

// ---------------- O = P * V^T (128x64 tile, BK=64 two-subtile) + LN partials ----------------
__launch_bounds__(256, 4)
__global__ void pv_kernel4(const f16* __restrict__ P, const f16* __restrict__ VT,
                           const float* __restrict__ gamma, const float* __restrict__ w_out,
                           float* __restrict__ part, int c0, int ch) {
    __shared__ __align__(16) char lds[24576];
    f16* As0 = (f16*)lds;                 // 128x32 = 8KB
    f16* As1 = (f16*)(lds + 8192);
    f16* Bs0 = (f16*)(lds + 16384);       // 64x32 = 4KB
    f16* Bs1 = (f16*)(lds + 20480);

    int tid = threadIdx.x;
    int w = tid >> 6, l = tid & 63;
    int wr = w >> 1, wc = w & 1;
    int lr = l & 15, lq = l >> 4;
    int srow = l >> 2, skg = (l & 3) * 8;
    int b = blockIdx.z;

    const f16* Abase = P  + ((size_t)b * ch + blockIdx.x * 128) * SEQ;
    const f16* Bbase = VT + (size_t)b * DIM * SEQ + (size_t)blockIdx.y * 64 * SEQ;

    f32x4 acc[4][2] = {};
    for (int k0 = 0; k0 < SEQ; k0 += 64) {
        __syncthreads();
        GLOAD16(Abase + (size_t)(w*16 + srow)*SEQ + k0 + skg,          As0 + w*512);
        GLOAD16(Abase + (size_t)((4+w)*16 + srow)*SEQ + k0 + skg,      As0 + (4+w)*512);
        GLOAD16(Abase + (size_t)(w*16 + srow)*SEQ + k0 + 32 + skg,     As1 + w*512);
        GLOAD16(Abase + (size_t)((4+w)*16 + srow)*SEQ + k0 + 32 + skg, As1 + (4+w)*512);
        GLOAD16(Bbase + (size_t)(w*16 + srow)*SEQ + k0 + skg,          Bs0 + w*512);
        GLOAD16(Bbase + (size_t)(w*16 + srow)*SEQ + k0 + 32 + skg,     Bs1 + w*512);
        __syncthreads();
        f16x8 a0[4], a1[4], b0[2], b1[2];
#pragma unroll
        for (int mt = 0; mt < 4; ++mt) {
            a0[mt] = *(const f16x8*)&As0[(wr*64 + mt*16 + lr)*32 + lq*8];
            a1[mt] = *(const f16x8*)&As1[(wr*64 + mt*16 + lr)*32 + lq*8];
        }
#pragma unroll
        for (int nt = 0; nt < 2; ++nt) {
            b0[nt] = *(const f16x8*)&Bs0[(wc*32 + nt*16 + lr)*32 + lq*8];
            b1[nt] = *(const f16x8*)&Bs1[(wc*32 + nt*16 + lr)*32 + lq*8];
        }
#pragma unroll
        for (int mt = 0; mt < 4; ++mt)
#pragma unroll
            for (int nt = 0; nt < 2; ++nt) {
                acc[mt][nt] = __builtin_amdgcn_mfma_f32_16x16x32_f16(a0[mt], b0[nt], acc[mt][nt], 0, 0, 0);
                acc[mt][nt] = __builtin_amdgcn_mfma_f32_16x16x32_f16(a1[mt], b1[nt], acc[mt][nt], 0, 0, 0);
            }
    }

    // LN partials: s1=sum(y), s2=sum(y^2), s3=sum(y*gamma*w)
    float gw[2];
#pragma unroll
    for (int nt = 0; nt < 2; ++nt) {
        int d = blockIdx.y * 64 + wc*32 + nt*16 + lr;
        gw[nt] = gamma[d] * w_out[d];
    }
    int tbase = b * SEQ + c0 + blockIdx.x * 128 + wr * 64;
#pragma unroll
    for (int mt = 0; mt < 4; ++mt)
#pragma unroll
        for (int q = 0; q < 4; ++q) {
            float s1 = 0.f, s2 = 0.f, s3 = 0.f;
#pragma unroll
            for (int nt = 0; nt < 2; ++nt) {
                float y = acc[mt][nt][q];
                s1 += y; s2 += y * y; s3 += y * gw[nt];
            }
#pragma unroll
            for (int m = 1; m <= 8; m <<= 1) {
                s1 += __shfl_xor(s1, m);
                s2 += __shfl_xor(s2, m);
                s3 += __shfl_xor(s3, m);
            }
            if (lr == 0) {
                int t = tbase + mt*16 + lq*4 + q;
                atomicAdd(&part[t*4 + 0], s1);
                atomicAdd(&part[t*4 + 1], s2);
                atomicAdd(&part[t*4 + 2], s3);
            }
        }
}

// ---------------- finalize: LN + dot ----------------
__launch_bounds__(256)
__global__ void finalize_kernel(const float* __restrict__ part,
                                const float* __restrict__ gamma, const float* __restrict__ beta,
                                const float* __restrict__ w_out, const float* __restrict__ b_out,
                                float* __restrict__ out) {
    int tid = threadIdx.x;
    float gw = 0.f, bw = 0.f;
    for (int d = tid; d < DIM; d += 256) { gw += gamma[d] * w_out[d]; bw += beta[d] * w_out[d]; }
#pragma unroll
    for (int m = 1; m < 64; m <<= 1) { gw += __shfl_xor(gw, m); bw += __shfl_xor(bw, m); }
    __shared__ float red[8];
    if ((tid & 63) == 0) { red[(tid >> 6)*2] = gw; red[(tid >> 6)*2 + 1] = bw; }
    __syncthreads();
    float SGW = red[0] + red[2] + red[4] + red[6];
    float SBW = red[1] + red[3] + red[5] + red[7];
    int t = blockIdx.x * 256 + tid;
    float S1 = part[t*4], S2 = part[t*4 + 1], S3 = part[t*4 + 2];
    const float inv_d = 1.0f / 768.0f;
    float mu = S1 * inv_d;
    float var = S2 * inv_d - mu * mu;
    float rstd = rsqrtf(var + 1e-5f);
    out[t] = rstd * (S3 - mu * SGW) + SBW + b_out[0];
}

// ---------------- launch ----------------
extern "C" void kernel_launch(void* const* d_in, const int* in_sizes, int n_in,
                              void* d_out, int out_size, void* d_ws, size_t ws_size,
                              hipStream_t stream) {
    const float* x     = (const float*)d_in[0];
    const float* Wq    = (const float*)d_in[1];
    const float* bq    = (const float*)d_in[2];
    const float* Wk    = (const float*)d_in[3];
    const float* bk    = (const float*)d_in[4];
    const float* Wv    = (const float*)d_in[5];
    const float* bv    = (const float*)d_in[6];
    const float* gamma = (const float*)d_in[7];
    const float* beta  = (const float*)d_in[8];
    const float* w_out = (const float*)d_in[9];
    const float* b_out = (const float*)d_in[10];
    float* out = (float*)d_out;
    char* ws = (char*)d_ws;

    const size_t SZM  = 25165824;        // one 16384x768 f16 matrix
    const size_t BASE = 3 * SZM;         // after Qh|Kh|VT = 75497472
    f16* Qh = (f16*)(ws);
    f16* Kh = (f16*)(ws + SZM);
    f16* VT = (f16*)(ws + 2*SZM);

    int ch; int vscatter; size_t off_wh;
    f16 *xh, *Vr, *Sc;
    const size_t NEED_A = BASE + 67108864 + 3538944 + 262144;       // CH=2048
    const size_t NEED_B = BASE + 33554432 + SZM + 3538944 + 262144; // CH=1024 + Vr
    const size_t NEED_C = BASE + 33554432 + 3538944 + 262144;       // CH=1024 scatter

    if (ws_size >= NEED_A) {
        ch = 2048; vscatter = 0;
        Sc = (f16*)(ws + BASE);
        xh = (f16*)(ws + BASE);
        Vr = (f16*)(ws + BASE + SZM);
        off_wh = BASE + 67108864;
    } else if (ws_size >= NEED_B) {
        ch = 1024; vscatter = 0;
        Sc = (f16*)(ws + BASE);
        xh = (f16*)(ws + BASE);
        Vr = (f16*)(ws + BASE + 33554432);
        off_wh = BASE + 33554432 + SZM;
    } else if (ws_size >= NEED_C) {
        ch = 1024; vscatter = 1;
        Sc = (f16*)(ws + BASE);
        xh = (f16*)(ws + BASE);
        Vr = VT;
        off_wh = BASE + 33554432;
    } else {
        return;
    }
    f16* Wh = (f16*)(ws + off_wh);
    float* part = (float*)(ws + off_wh + 3538944);

    zero_kernel<<<256, 256, 0, stream>>>(part, 65536);
    cvt_kernel<<<2048, 256, 0, stream>>>(x, xh, TOK * DIM / 4);
    cvt_kernel<<<512, 256, 0, stream>>>(Wq, Wh,               DIM * DIM / 4);
    cvt_kernel<<<512, 256, 0, stream>>>(Wk, Wh + DIM * DIM,   DIM * DIM / 4);
    cvt_kernel<<<512, 256, 0, stream>>>(Wv, Wh + 2*DIM*DIM,   DIM * DIM / 4);

    proj_kernel4<<<dim3(TOK/128, 18), 256, 0, stream>>>(xh, Wh, bq, bk, bv, Qh, Kh, Vr, vscatter);
    if (!vscatter)
        transpose_v<<<dim3(SEQ/64, DIM/64, BATCH), 256, 0, stream>>>(Vr, VT);

    int nch = SEQ / ch;
    for (int c = 0; c < nch; ++c) {
        int c0 = c * ch;
        qkt_kernel4<<<dim3(ch/128, SEQ/128, BATCH), 256, 0, stream>>>(Qh, Kh, Sc, c0, ch);
        softmax_kernel<<<BATCH * ch, 256, 0, stream>>>(Sc);
        pv_kernel4<<<dim3(ch/128, DIM/64, BATCH), 256, 0, stream>>>(Sc, VT, gamma, w_out, part, c0, ch);
    }
    finalize_kernel<<<TOK/256, 256, 0, stream>>>(part, gamma, beta, w_out, b_out, out);
}